// Round 5
// baseline (82.806 us; speedup 1.0000x reference)
//
#include <hip/hip_runtime.h>

// GaussianBasis: 2D gaussian splatting, N=10000 gaussians -> (3,256,256) fp32.
// v5 — 2-node scan-gather with CHEAP compaction (no global atomics, no memset):
//   prep:   per-gaussian params (3 x float4) + packed tile-range u32.
//           Sentinel 0x7C1F (tx0=31 > tx1=0) never matches any tile
//           (v3's 0xFFFFFFFF decoded to tile 31,31 - latent bug).
//   render: 1024 blocks (one 8x8 tile each) x 256 thr. Scan the 10000 packed
//           ranges; matches go to PER-THREAD private LDS slots (transposed
//           [slot][tid] layout -> conflict-free) with zero cross-lane ops in
//           the loop (v3's ballot+LDS-atomic+shfl chain was ~165 cyc/iter x40).
//           One 256-wide Hillis-Steele prefix-sum then compacts to the block
//           list; inner eval loop is the proven v2 structure (wave-strided j,
//           LDS broadcast, register RGB accum, cross-wave reduce, fused
//           scale/shift store).

#define IMG_H 256
#define IMG_W 256
#define TILE 8
#define TPX 32          // tiles per axis (256/8)
#define NTILES 1024
#define CAP 512         // max gaussians per tile (worst observed ~150-300)
#define PRIV 16         // per-thread private match slots (P[overflow] ~ 1e-13)

__global__ __launch_bounds__(256) void prep_kernel(
    const float* __restrict__ xyz,      // (N,2)
    const float* __restrict__ chol,     // (N,3)
    const float* __restrict__ colors,   // (N,3)
    const float* __restrict__ opacity,  // (N,1)
    int N,
    unsigned int* __restrict__ bbox,    // [N] packed tile ranges
    float4* __restrict__ params)        // [N][3]: (cx,cy,a,b)(c,op,c0,c1)(c2,-,-,-)
{
    const int n = blockIdx.x * 256 + threadIdx.x;
    if (n >= N) return;

    const float mx = tanhf(xyz[2 * n + 0]);
    const float my = tanhf(xyz[2 * n + 1]);
    const float cx = 0.5f * IMG_W * (mx + 1.0f);
    const float cy = 0.5f * IMG_H * (my + 1.0f);

    const float L0 = chol[3 * n + 0] + 0.5f;
    const float L1 = chol[3 * n + 1];
    const float L2 = chol[3 * n + 2] + 0.5f;
    const float cov_xx = L0 * L0;
    const float cov_xy = L0 * L1;
    const float cov_yy = L1 * L1 + L2 * L2;
    const float det = cov_xx * cov_yy - cov_xy * cov_xy;  // = (L0*L2)^2 > 0

    const float op = opacity[n];
    params[3 * n + 0] = make_float4(cx, cy, cov_yy / det, -cov_xy / det);
    params[3 * n + 1] = make_float4(cov_xx / det, op,
                                    colors[3 * n + 0], colors[3 * n + 1]);
    params[3 * n + 2] = make_float4(colors[3 * n + 2], 0.0f, 0.0f, 0.0f);

    // alpha = op*exp(-sigma) >= 1/255  =>  sigma <= log(255*op) = smax
    const float smax = logf(255.0f * op);
    unsigned int packed = 31u | (31u << 10);  // 0x7C1F: tx0=31 > tx1=0, never matches
    if (smax > 0.0f) {
        const float rx = sqrtf(2.0f * smax * cov_xx) + 1.0f;
        const float ry = sqrtf(2.0f * smax * cov_yy) + 1.0f;
        const int x0 = max(0, (int)floorf(cx - rx));
        const int x1 = min(IMG_W - 1, (int)ceilf(cx + rx));
        const int y0 = max(0, (int)floorf(cy - ry));
        const int y1 = min(IMG_H - 1, (int)ceilf(cy + ry));
        if (x0 <= x1 && y0 <= y1) {
            packed = (unsigned int)(x0 >> 3) | ((unsigned int)(x1 >> 3) << 5) |
                     ((unsigned int)(y0 >> 3) << 10) | ((unsigned int)(y1 >> 3) << 15);
        }
    }
    bbox[n] = packed;
}

__global__ __launch_bounds__(256) void render_kernel(
    const unsigned int* __restrict__ bbox,
    const float4* __restrict__ params,
    const float* __restrict__ scale,
    const float* __restrict__ shift,
    int N,
    float* __restrict__ out)
{
    // Bijective tile scatter (389 odd => invertible mod 1024): spreads heavy
    // border tiles (tanh piles mass at edges) across CUs/XCDs.
    const int tile = (blockIdx.x * 389) & (NTILES - 1);
    const int tx = tile & (TPX - 1);
    const int ty = tile >> 5;
    const int wave = threadIdx.x >> 6;   // 0..3: gaussian slice
    const int p = threadIdx.x & 63;      // pixel within 8x8 tile
    const float px = (float)(tx * TILE + (p & (TILE - 1)));
    const float py = (float)(ty * TILE + (p >> 3));

    __shared__ int lpriv[PRIV][256];     // transposed: write lpriv[c][tid] -> bank = tid%32, conflict-free
    __shared__ int pscan[256];
    __shared__ int lidx[CAP];
    __shared__ float4 sh4[2 * 256];      // (cx,cy,a,b),(c,op,c0,c1) per gaussian
    __shared__ float shc[256];           // c2 per gaussian
    __shared__ float red[3][256];        // cross-wave reduction

    // --- scan: zero cross-lane ops in the loop ---
    const unsigned int txu = (unsigned int)tx;
    const unsigned int tyu = (unsigned int)ty;
    int c = 0;
#pragma unroll 4
    for (int k = 0; k < 40; ++k) {       // ceil(10000/256); guarded below
        const int i = threadIdx.x + (k << 8);
        if (i < N) {
            const unsigned int b = bbox[i];  // coalesced; 40 KB total, L2-resident
            const bool match = ((b & 31u) <= txu) & (txu <= ((b >> 5) & 31u)) &
                               (((b >> 10) & 31u) <= tyu) & (tyu <= ((b >> 15) & 31u));
            if (match && c < PRIV) { lpriv[c][threadIdx.x] = i; ++c; }
        }
    }

    // --- exclusive offsets via 256-wide Hillis-Steele inclusive scan ---
    pscan[threadIdx.x] = c;
    __syncthreads();
    for (int d = 1; d < 256; d <<= 1) {
        int y = 0;
        if (threadIdx.x >= d) y = pscan[threadIdx.x - d];
        __syncthreads();
        if (threadIdx.x >= d) pscan[threadIdx.x] += y;
        __syncthreads();
    }
    const int cnt = min(pscan[255], CAP);
    const int off = pscan[threadIdx.x] - c;
    for (int k = 0; k < c; ++k) {
        const int s = off + k;
        if (s < CAP) lidx[s] = lpriv[k][threadIdx.x];
    }
    __syncthreads();

    // --- staged eval (v2 structure) ---
    float accr = 0.0f, accg = 0.0f, accb = 0.0f;

    for (int base = 0; base < cnt; base += 256) {
        const int m = min(256, cnt - base);
        if (threadIdx.x < m) {
            const int n = lidx[base + threadIdx.x];
            sh4[2 * threadIdx.x + 0] = params[3 * n + 0];
            sh4[2 * threadIdx.x + 1] = params[3 * n + 1];
            shc[threadIdx.x] = params[3 * n + 2].x;
        }
        __syncthreads();
        // wave s handles j = s, s+4, ... : uniform j within a wave ->
        // LDS broadcast reads; each list entry touched by exactly one wave.
#pragma unroll 2
        for (int j = wave; j < m; j += 4) {
            const float4 p0 = sh4[2 * j + 0];  // cx, cy, a, b
            const float4 p1 = sh4[2 * j + 1];  // c, op, col0, col1
            const float c2v = shc[j];
            const float dx = p0.x - px;
            const float dy = p0.y - py;
            const float sigma =
                0.5f * (p0.z * dx * dx + p1.x * dy * dy) + p0.w * (dx * dy);
            float alpha = p1.y * __expf(-sigma);
            if (sigma >= 0.0f && alpha >= (1.0f / 255.0f)) {
                alpha = fminf(alpha, 0.999f);
                accr = fmaf(alpha, p1.z, accr);
                accg = fmaf(alpha, p1.w, accg);
                accb = fmaf(alpha, c2v, accb);
            }
        }
        __syncthreads();
    }

    red[0][threadIdx.x] = accr;
    red[1][threadIdx.x] = accg;
    red[2][threadIdx.x] = accb;
    __syncthreads();

    // threads 0..191: c = t>>6, pixel = t&63 ; sum the 4 wave-partials.
    if (threadIdx.x < 192) {
        const int ch = threadIdx.x >> 6;
        const int q = threadIdx.x & 63;
        const float sum = red[ch][q] + red[ch][q + 64] + red[ch][q + 128] + red[ch][q + 192];
        const int pix = (ty * TILE + (q >> 3)) * IMG_W + tx * TILE + (q & (TILE - 1));
        out[ch * IMG_H * IMG_W + pix] = fmaf(sum, scale[0], shift[0]);
    }
}

extern "C" void kernel_launch(void* const* d_in, const int* in_sizes, int n_in,
                              void* d_out, int out_size, void* d_ws, size_t ws_size,
                              hipStream_t stream) {
    const float* xyz     = (const float*)d_in[0];
    const float* chol    = (const float*)d_in[1];
    const float* colors  = (const float*)d_in[2];
    const float* opacity = (const float*)d_in[3];
    const float* scale   = (const float*)d_in[4];
    const float* shift   = (const float*)d_in[5];
    float* out = (float*)d_out;

    const int N = in_sizes[3];  // opacity is (N,1)

    // ws layout: bbox [N u32] | params [N*3 float4] (N*4 = 40000 is 16B-aligned)
    unsigned int* bbox = (unsigned int*)d_ws;
    float4* params = (float4*)((char*)d_ws + ((N * 4 + 15) & ~15));

    prep_kernel<<<(N + 255) / 256, 256, 0, stream>>>(
        xyz, chol, colors, opacity, N, bbox, params);
    render_kernel<<<NTILES, 256, 0, stream>>>(bbox, params, scale, shift, N, out);
}

// Round 6
// 76.422 us; speedup vs baseline: 1.0835x; 1.0835x over previous
//
#include <hip/hip_runtime.h>

// GaussianBasis: 2D gaussian splatting, N=10000 gaussians -> (3,256,256) fp32.
// v6 = exact revert to v2, the best-measured variant (76.4 us).
// Session evidence:
//   v0 scatter-atomics 81.7 | v1 16x16 gather (contended bins) 100.1
//   v2 8x8 gather, padded counters 76.4 | v3 scan+ballot 83.9
//   v4 v2+hash-scatter+unroll 76.9 (noise) | v5 scan+private-slots 82.8
// Lessons baked in:
//   - binned per-tile lists beat per-block scans (scan loop latency + prefix
//     overhead ~6 us > the 1-2 us saved by dropping nodes/atomics);
//   - binning counters MUST be padded to one per 64B line (v1's +24 us);
//   - 8x8 tiles: each list entry is evaluated by exactly ONE wave, 4 blocks/CU;
//   - remaining time is harness-fixed: 256 MiB poison fill (~40 us @ 84% HBM
//     peak) + reset dispatches; our 3 dispatches total ~6 us.

#define IMG_H 256
#define IMG_W 256
#define TILE 8
#define TPX 32          // tiles per axis (256/8)
#define NTILES 1024
#define CAP 512         // max gaussians per tile list (worst observed ~150)
#define CSTRIDE 16      // counter padding: 16 ints = 64 B line per counter

__global__ __launch_bounds__(64) void prep_bin_kernel(
    const float* __restrict__ xyz,      // (N,2)
    const float* __restrict__ chol,     // (N,3)
    const float* __restrict__ colors,   // (N,3)
    const float* __restrict__ opacity,  // (N,1)
    int N,
    int* __restrict__ counts,           // [NTILES*CSTRIDE]
    int* __restrict__ lists,            // [NTILES][CAP]
    float4* __restrict__ params)        // [N][3]: (cx,cy,a,b)(c,op,c0,c1)(c2,-,-,-)
{
    const int n = blockIdx.x * 64 + threadIdx.x;
    if (n >= N) return;

    const float mx = tanhf(xyz[2 * n + 0]);
    const float my = tanhf(xyz[2 * n + 1]);
    const float cx = 0.5f * IMG_W * (mx + 1.0f);
    const float cy = 0.5f * IMG_H * (my + 1.0f);

    const float L0 = chol[3 * n + 0] + 0.5f;
    const float L1 = chol[3 * n + 1];
    const float L2 = chol[3 * n + 2] + 0.5f;
    const float cov_xx = L0 * L0;
    const float cov_xy = L0 * L1;
    const float cov_yy = L1 * L1 + L2 * L2;
    const float det = cov_xx * cov_yy - cov_xy * cov_xy;  // = (L0*L2)^2 > 0

    const float op = opacity[n];
    params[3 * n + 0] = make_float4(cx, cy, cov_yy / det, -cov_xy / det);
    params[3 * n + 1] = make_float4(cov_xx / det, op,
                                    colors[3 * n + 0], colors[3 * n + 1]);
    params[3 * n + 2] = make_float4(colors[3 * n + 2], 0.0f, 0.0f, 0.0f);

    // alpha = op*exp(-sigma) >= 1/255  =>  sigma <= log(255*op) = smax
    const float smax = logf(255.0f * op);
    if (!(smax > 0.0f)) return;  // never visible

    const float rx = sqrtf(2.0f * smax * cov_xx) + 1.0f;
    const float ry = sqrtf(2.0f * smax * cov_yy) + 1.0f;
    const int x0 = max(0, (int)floorf(cx - rx));
    const int x1 = min(IMG_W - 1, (int)ceilf(cx + rx));
    const int y0 = max(0, (int)floorf(cy - ry));
    const int y1 = min(IMG_H - 1, (int)ceilf(cy + ry));
    if (x0 > x1 || y0 > y1) return;

    const int tx0 = x0 >> 3, tx1 = x1 >> 3;
    const int ty0 = y0 >> 3, ty1 = y1 >> 3;
    for (int ty = ty0; ty <= ty1; ++ty) {
        for (int tx = tx0; tx <= tx1; ++tx) {
            const int t = ty * TPX + tx;
            const int slot = atomicAdd(&counts[t * CSTRIDE], 1);
            if (slot < CAP) lists[t * CAP + slot] = n;
        }
    }
}

__global__ __launch_bounds__(256) void render_kernel(
    const int* __restrict__ counts,
    const int* __restrict__ lists,
    const float4* __restrict__ params,
    const float* __restrict__ scale,
    const float* __restrict__ shift,
    float* __restrict__ out)
{
    const int tile = blockIdx.x;
    const int tx = tile & (TPX - 1);
    const int ty = tile >> 5;
    const int wave = threadIdx.x >> 6;   // 0..3: gaussian slice
    const int p = threadIdx.x & 63;      // pixel within 8x8 tile
    const float px = (float)(tx * TILE + (p & (TILE - 1)));
    const float py = (float)(ty * TILE + (p >> 3));

    __shared__ float4 sh[3 * 256];       // 12 KB staged params
    __shared__ float red[3][256];        // 3 KB cross-wave reduction

    const int cnt = min(counts[tile * CSTRIDE], CAP);
    const int* list = lists + tile * CAP;

    float accr = 0.0f, accg = 0.0f, accb = 0.0f;

    for (int base = 0; base < cnt; base += 256) {
        const int m = min(256, cnt - base);
        __syncthreads();
        if (threadIdx.x < m) {
            const int n = list[base + threadIdx.x];
            sh[3 * threadIdx.x + 0] = params[3 * n + 0];
            sh[3 * threadIdx.x + 1] = params[3 * n + 1];
            sh[3 * threadIdx.x + 2] = params[3 * n + 2];
        }
        __syncthreads();
        // wave s handles j = s, s+4, ... : uniform j within a wave ->
        // LDS broadcast reads, and each list entry is touched by ONE wave.
        for (int j = wave; j < m; j += 4) {
            const float4 p0 = sh[3 * j + 0];  // cx, cy, a, b
            const float4 p1 = sh[3 * j + 1];  // c, op, col0, col1
            const float c2v = sh[3 * j + 2].x;
            const float dx = p0.x - px;
            const float dy = p0.y - py;
            const float sigma =
                0.5f * (p0.z * dx * dx + p1.x * dy * dy) + p0.w * (dx * dy);
            float alpha = p1.y * __expf(-sigma);
            if (sigma >= 0.0f && alpha >= (1.0f / 255.0f)) {
                alpha = fminf(alpha, 0.999f);
                accr = fmaf(alpha, p1.z, accr);
                accg = fmaf(alpha, p1.w, accg);
                accb = fmaf(alpha, c2v, accb);
            }
        }
    }

    red[0][threadIdx.x] = accr;
    red[1][threadIdx.x] = accg;
    red[2][threadIdx.x] = accb;
    __syncthreads();

    // threads 0..191: c = t>>6, pixel = t&63 ; sum the 4 wave-partials.
    if (threadIdx.x < 192) {
        const int c = threadIdx.x >> 6;
        const int q = threadIdx.x & 63;
        const float sum = red[c][q] + red[c][q + 64] + red[c][q + 128] + red[c][q + 192];
        const int pix = (ty * TILE + (q >> 3)) * IMG_W + tx * TILE + (q & (TILE - 1));
        out[c * IMG_H * IMG_W + pix] = fmaf(sum, scale[0], shift[0]);
    }
}

extern "C" void kernel_launch(void* const* d_in, const int* in_sizes, int n_in,
                              void* d_out, int out_size, void* d_ws, size_t ws_size,
                              hipStream_t stream) {
    const float* xyz     = (const float*)d_in[0];
    const float* chol    = (const float*)d_in[1];
    const float* colors  = (const float*)d_in[2];
    const float* opacity = (const float*)d_in[3];
    const float* scale   = (const float*)d_in[4];
    const float* shift   = (const float*)d_in[5];
    float* out = (float*)d_out;

    const int N = in_sizes[3];  // opacity is (N,1)

    // ws layout: counts [NTILES*CSTRIDE ints = 64 KB] | lists [NTILES*CAP ints = 2 MB]
    //            | params [N*3 float4 = 480 KB]
    int* counts = (int*)d_ws;
    int* lists = counts + NTILES * CSTRIDE;
    float4* params = (float4*)(lists + NTILES * CAP);  // 16B-aligned offset

    hipMemsetAsync(counts, 0, NTILES * CSTRIDE * sizeof(int), stream);
    prep_bin_kernel<<<(N + 63) / 64, 64, 0, stream>>>(
        xyz, chol, colors, opacity, N, counts, lists, params);
    render_kernel<<<NTILES, 256, 0, stream>>>(counts, lists, params, scale, shift, out);
}